// Round 1
// baseline (528.733 us; speedup 1.0000x reference)
//
#include <hip/hip_runtime.h>
#include <math.h>

#define A_DIM 128   // image height/width
#define N_G   64    // glimpse size
#define HD    512   // h_dim
#define T_LD  132   // padded LDS leading dim for T (132*4B = 528B, 16B-aligned rows)

// Builds the two filterbanks from params = W_read(h[0]).
// FYT[a*64+n] = gamma * F_Y[n][a] / sum(F_Y)   (gamma folded in)
// FXT[c*64+m] =          F_X[m][c] / sum(F_X)
__global__ __launch_bounds__(512) void fb_setup_kernel(
    const float* __restrict__ h, const float* __restrict__ Ww,
    const float* __restrict__ Wb, float* __restrict__ FYT,
    float* __restrict__ FXT) {
  __shared__ float p[5];
  __shared__ float redX[8], redY[8];
  __shared__ float invs[2];
  const int tid = threadIdx.x, wave = tid >> 6, lane = tid & 63;

  // params[j] = h[0,:] . Ww[j,:] + Wb[j]  -- one wave per param
  if (wave < 5) {
    float s = 0.f;
    for (int k = lane; k < HD; k += 64) s += h[k] * Ww[wave * HD + k];
#pragma unroll
    for (int off = 32; off > 0; off >>= 1) s += __shfl_down(s, off);
    if (lane == 0) p[wave] = s + Wb[wave];
  }
  __syncthreads();

  const float gX = 64.5f * (p[0] + 1.0f);       // (A+1)*(gt_X+1)/2
  const float gY = 64.5f * (p[1] + 1.0f);
  const float var = expf(p[2] + 1e-8f);
  const float dd = expf(p[3]) * (127.0f / 63.0f);
  const float gamma = expf(p[4]);
  const float two_var = 2.0f * var;

  // global sums of unnormalized F_X, F_Y
  float sX = 0.f, sY = 0.f;
  for (int i = tid; i < N_G * A_DIM; i += 512) {
    const int n = i >> 7, a = i & 127;
    const float off_n = ((float)n - 32.5f) * dd;   // (i - N/2 - 0.5)*d
    const float tx = (float)a - (gX + off_n);
    const float ty = (float)a - (gY + off_n);
    sX += expf(-(tx * tx) / two_var);
    sY += expf(-(ty * ty) / two_var);
  }
#pragma unroll
  for (int off = 32; off > 0; off >>= 1) {
    sX += __shfl_down(sX, off);
    sY += __shfl_down(sY, off);
  }
  if (lane == 0) { redX[wave] = sX; redY[wave] = sY; }
  __syncthreads();
  if (tid == 0) {
    float tX = 0.f, tY = 0.f;
#pragma unroll
    for (int w = 0; w < 8; ++w) { tX += redX[w]; tY += redY[w]; }
    invs[0] = 1.0f / tX;
    invs[1] = gamma / tY;
  }
  __syncthreads();
  const float isX = invs[0], isYg = invs[1];

  for (int i = tid; i < N_G * A_DIM; i += 512) {
    const int n = i >> 7, a = i & 127;
    const float off_n = ((float)n - 32.5f) * dd;
    const float tx = (float)a - (gX + off_n);
    const float ty = (float)a - (gY + off_n);
    FXT[a * N_G + n] = expf(-(tx * tx) / two_var) * isX;
    FYT[a * N_G + n] = expf(-(ty * ty) / two_var) * isYg;
  }
}

// One block per (batch, tensor) image.
// Phase 1: T[n][c] = sum_a FY[n][a]*src[a][c]   (T in LDS, padded ld=132)
// Phase 2: out[n][m] = sum_c T[n][c]*FX[m][c]
__global__ __launch_bounds__(256) void glimpse_kernel(
    const float* __restrict__ x, const float* __restrict__ xh,
    const float* __restrict__ FYT, const float* __restrict__ FXT,
    float* __restrict__ out) {
  const int img = blockIdx.x;
  const int b = img >> 1, t = img & 1;
  const float* __restrict__ src = (t ? xh : x) + (size_t)b * (A_DIM * A_DIM);
  float* __restrict__ dst = out + (size_t)b * (2 * N_G * N_G) + t * (N_G * N_G);

  __shared__ float Tl[N_G * T_LD];
  const int tid = threadIdx.x;

  // ---------- phase 1 ----------
  {
    const int tx = tid & 15;  // c0 = tx*8 (8 columns per thread)
    const int ty = tid >> 4;  // n0 = ty*4 (4 glimpse rows per thread)
    float acc[4][8];
#pragma unroll
    for (int i = 0; i < 4; ++i)
#pragma unroll
      for (int j = 0; j < 8; ++j) acc[i][j] = 0.f;

    const float* fp = FYT + ty * 4;
    const float* xp = src + tx * 8;
#pragma unroll 4
    for (int a = 0; a < A_DIM; ++a) {
      const float4 f = *(const float4*)(fp + a * N_G);
      const float4 x0 = *(const float4*)(xp + a * A_DIM);
      const float4 x1 = *(const float4*)(xp + a * A_DIM + 4);
      const float fv[4] = {f.x, f.y, f.z, f.w};
      const float xv[8] = {x0.x, x0.y, x0.z, x0.w, x1.x, x1.y, x1.z, x1.w};
#pragma unroll
      for (int i = 0; i < 4; ++i)
#pragma unroll
        for (int j = 0; j < 8; ++j) acc[i][j] += fv[i] * xv[j];
    }
#pragma unroll
    for (int i = 0; i < 4; ++i) {
      float* dl = &Tl[(ty * 4 + i) * T_LD + tx * 8];
      *(float4*)(dl) = make_float4(acc[i][0], acc[i][1], acc[i][2], acc[i][3]);
      *(float4*)(dl + 4) = make_float4(acc[i][4], acc[i][5], acc[i][6], acc[i][7]);
    }
  }
  __syncthreads();

  // ---------- phase 2 ----------
  {
    const int tx = tid & 15;  // m0 = tx*4
    const int ty = tid >> 4;  // n0 = ty*4
    float acc[4][4];
#pragma unroll
    for (int i = 0; i < 4; ++i)
#pragma unroll
      for (int j = 0; j < 4; ++j) acc[i][j] = 0.f;

#pragma unroll 4
    for (int c = 0; c < A_DIM; ++c) {
      const float4 f = *(const float4*)(FXT + c * N_G + tx * 4);
      const float fv[4] = {f.x, f.y, f.z, f.w};
#pragma unroll
      for (int i = 0; i < 4; ++i) {
        const float tv = Tl[(ty * 4 + i) * T_LD + c];
#pragma unroll
        for (int j = 0; j < 4; ++j) acc[i][j] += tv * fv[j];
      }
    }
#pragma unroll
    for (int i = 0; i < 4; ++i)
      *(float4*)(dst + (ty * 4 + i) * N_G + tx * 4) =
          make_float4(acc[i][0], acc[i][1], acc[i][2], acc[i][3]);
  }
}

extern "C" void kernel_launch(void* const* d_in, const int* in_sizes, int n_in,
                              void* d_out, int out_size, void* d_ws, size_t ws_size,
                              hipStream_t stream) {
  const float* x  = (const float*)d_in[0];   // (2048, 16384)
  const float* xh = (const float*)d_in[1];   // (2048, 16384)
  const float* h  = (const float*)d_in[2];   // (2048, 512) -- only row 0 used
  const float* Ww = (const float*)d_in[3];   // (5, 512)
  const float* Wb = (const float*)d_in[4];   // (5,)
  float* out = (float*)d_out;                // (2048, 8192)

  float* FYT = (float*)d_ws;                 // 64*128 floats
  float* FXT = FYT + N_G * A_DIM;            // 64*128 floats

  fb_setup_kernel<<<1, 512, 0, stream>>>(h, Ww, Wb, FYT, FXT);
  glimpse_kernel<<<4096, 256, 0, stream>>>(x, xh, FYT, FXT, out);
}

// Round 2
// 313.397 us; speedup vs baseline: 1.6871x; 1.6871x over previous
//
#include <hip/hip_runtime.h>
#include <math.h>

#define A_DIM 128   // image height/width
#define N_G   64    // glimpse size
#define HD    512   // h_dim
#define LDX   136   // padded LDS leading dim (bf16 elems): 272 B/row -> 4-bank shift/row, 2-way = free

typedef short short8 __attribute__((ext_vector_type(8)));   // 8 bf16 = 4 VGPRs (MFMA A/B frag)
typedef float floatx4 __attribute__((ext_vector_type(4)));  // MFMA C/D frag

static __device__ __forceinline__ unsigned short f2bf(float f) {
  union { float f; unsigned u; } v; v.f = f;
  unsigned r = (v.u + 0x7fffu + ((v.u >> 16) & 1u)) >> 16;   // RNE
  return (unsigned short)r;
}

// Builds pre-swizzled MFMA fragment tables in d_ws:
//  FXfrag[tile_n][kk][lane][j] = FX[m = tile_n*16 + (lane&15)][c = kk*32 + (lane>>4)*8 + j] / sumX
//      (B-operand for phase A:  U = x @ FX^T)
//  FYfrag[tile_n][kk][lane][j] = gamma * FY[n = tile_n*16 + (lane&15)][a = kk*32 + (lane>>4)*8 + j] / sumY
//      (A-operand for phase B:  out = FY @ U)
__global__ __launch_bounds__(512) void fb_setup_kernel(
    const float* __restrict__ h, const float* __restrict__ Ww,
    const float* __restrict__ Wb, unsigned short* __restrict__ FXfrag,
    unsigned short* __restrict__ FYfrag) {
  __shared__ float p[5];
  __shared__ float redX[8], redY[8];
  __shared__ float invs[2];
  const int tid = threadIdx.x, wave = tid >> 6, lane = tid & 63;

  if (wave < 5) {
    float s = 0.f;
    for (int k = lane; k < HD; k += 64) s += h[k] * Ww[wave * HD + k];
#pragma unroll
    for (int off = 32; off > 0; off >>= 1) s += __shfl_down(s, off);
    if (lane == 0) p[wave] = s + Wb[wave];
  }
  __syncthreads();

  const float gX = 64.5f * (p[0] + 1.0f);
  const float gY = 64.5f * (p[1] + 1.0f);
  const float var = expf(p[2] + 1e-8f);
  const float dd = expf(p[3]) * (127.0f / 63.0f);
  const float gamma = expf(p[4]);
  const float two_var = 2.0f * var;

  float sX = 0.f, sY = 0.f;
  for (int i = tid; i < N_G * A_DIM; i += 512) {
    const int n = i >> 7, a = i & 127;
    const float off_n = ((float)n - 32.5f) * dd;
    const float tx = (float)a - (gX + off_n);
    const float ty = (float)a - (gY + off_n);
    sX += expf(-(tx * tx) / two_var);
    sY += expf(-(ty * ty) / two_var);
  }
#pragma unroll
  for (int off = 32; off > 0; off >>= 1) {
    sX += __shfl_down(sX, off);
    sY += __shfl_down(sY, off);
  }
  if (lane == 0) { redX[wave] = sX; redY[wave] = sY; }
  __syncthreads();
  if (tid == 0) {
    float tX = 0.f, tY = 0.f;
#pragma unroll
    for (int w = 0; w < 8; ++w) { tX += redX[w]; tY += redY[w]; }
    invs[0] = 1.0f / tX;
    invs[1] = gamma / tY;
  }
  __syncthreads();
  const float isX = invs[0], isYg = invs[1];

  // 8192 fragment elements per table: i = tile*2048 + kk*512 + lane*8 + j
  for (int i = tid; i < 4 * 4 * 64 * 8; i += 512) {
    const int j = i & 7;
    const int ln = (i >> 3) & 63;
    const int kk = (i >> 9) & 3;
    const int tl = (i >> 11) & 3;
    const int mn = tl * 16 + (ln & 15);          // m (for FX) / n (for FY)
    const int ca = kk * 32 + ((ln >> 4) << 3) + j;  // c (for FX) / a (for FY)
    const float off_mn = ((float)mn - 32.5f) * dd;
    const float tx = (float)ca - (gX + off_mn);
    const float ty = (float)ca - (gY + off_mn);
    FXfrag[i] = f2bf(expf(-(tx * tx) / two_var) * isX);
    FYfrag[i] = f2bf(expf(-(ty * ty) / two_var) * isYg);
  }
}

// One block (256 thr, 4 waves) per (batch, tensor) image.
// Phase A: U[a][m] = sum_c x[a][c] * FX[m][c]      (MFMA, A = x from LDS, B = FXfrag)
//          -> written to LDS as bf16 U^T[m][a]
// Phase B: out[n][m] = sum_a FY[n][a] * U[a][m]    (MFMA, A = FYfrag, B = U^T from LDS)
__global__ __launch_bounds__(256) void glimpse_kernel(
    const float* __restrict__ x, const float* __restrict__ xh,
    const unsigned short* __restrict__ FXfrag,
    const unsigned short* __restrict__ FYfrag,
    float* __restrict__ out) {
  const int img = blockIdx.x;
  const int b = img >> 1, t = img & 1;
  const float* __restrict__ src = (t ? xh : x) + (size_t)b * (A_DIM * A_DIM);
  float* __restrict__ dst = out + (size_t)b * (2 * N_G * N_G) + t * (N_G * N_G);

  __shared__ __align__(16) unsigned short xs[A_DIM * LDX];  // x as bf16, row-major [a][c]
  __shared__ __align__(16) unsigned short us[N_G * LDX];    // U^T as bf16, [m][a]

  const int tid = threadIdx.x;
  const int w = tid >> 6, lane = tid & 63;
  const int quad = lane >> 4, lm = lane & 15;

  // ---- stage x -> bf16 LDS (fp32 float4 coalesced loads, on-the-fly convert) ----
  {
    const float4* __restrict__ src4 = (const float4*)src;
#pragma unroll
    for (int it = 0; it < 16; ++it) {
      const int flat = it * 256 + tid;       // 4096 float4 total
      const int a = flat >> 5;               // 32 float4 per row
      const int c4 = (flat & 31) * 4;
      const float4 v = src4[flat];
      uint2 pk;
      pk.x = (unsigned)f2bf(v.x) | ((unsigned)f2bf(v.y) << 16);
      pk.y = (unsigned)f2bf(v.z) | ((unsigned)f2bf(v.w) << 16);
      *(uint2*)&xs[a * LDX + c4] = pk;
    }
  }
  __syncthreads();

  // ---- phase A: U = x @ FX^T.  Wave w owns a-rows [w*32, w*32+32) = tiles tm = 2w, 2w+1 ----
  {
    floatx4 acc[2][4];
#pragma unroll
    for (int i = 0; i < 2; ++i)
#pragma unroll
      for (int j = 0; j < 4; ++j) acc[i][j] = (floatx4)0.f;

#pragma unroll
    for (int kk = 0; kk < 4; ++kk) {
      short8 aF[2], bF[4];
#pragma unroll
      for (int i = 0; i < 2; ++i)
        aF[i] = *(const short8*)&xs[((2 * w + i) * 16 + lm) * LDX + kk * 32 + quad * 8];
#pragma unroll
      for (int j = 0; j < 4; ++j)
        bF[j] = *(const short8*)(FXfrag + ((size_t)(j * 4 + kk) * 64 + lane) * 8);
#pragma unroll
      for (int i = 0; i < 2; ++i)
#pragma unroll
        for (int j = 0; j < 4; ++j)
          acc[i][j] = __builtin_amdgcn_mfma_f32_16x16x32_bf16(aF[i], bF[j], acc[i][j], 0, 0, 0);
    }

    // write U^T[m][a] as bf16: lane holds (a = tm*16 + quad*4 + r, m = tn*16 + lm), r=0..3
#pragma unroll
    for (int i = 0; i < 2; ++i)
#pragma unroll
      for (int j = 0; j < 4; ++j) {
        uint2 pk;
        pk.x = (unsigned)f2bf(acc[i][j][0]) | ((unsigned)f2bf(acc[i][j][1]) << 16);
        pk.y = (unsigned)f2bf(acc[i][j][2]) | ((unsigned)f2bf(acc[i][j][3]) << 16);
        *(uint2*)&us[(j * 16 + lm) * LDX + (2 * w + i) * 16 + quad * 4] = pk;
      }
  }
  __syncthreads();

  // ---- phase B: out = FY @ U.  Wave w owns n-tile w, all 4 m-tiles ----
  {
    floatx4 acc2[4];
#pragma unroll
    for (int j = 0; j < 4; ++j) acc2[j] = (floatx4)0.f;

#pragma unroll
    for (int kk = 0; kk < 4; ++kk) {
      const short8 aF = *(const short8*)(FYfrag + ((size_t)(w * 4 + kk) * 64 + lane) * 8);
#pragma unroll
      for (int mt = 0; mt < 4; ++mt) {
        const short8 bF = *(const short8*)&us[(mt * 16 + lm) * LDX + kk * 32 + quad * 8];
        acc2[mt] = __builtin_amdgcn_mfma_f32_16x16x32_bf16(aF, bF, acc2[mt], 0, 0, 0);
      }
    }

    // D layout: row(n) = quad*4 + r within tile, col(m) = lm
#pragma unroll
    for (int mt = 0; mt < 4; ++mt)
#pragma unroll
      for (int r = 0; r < 4; ++r)
        dst[(w * 16 + quad * 4 + r) * N_G + mt * 16 + lm] = acc2[mt][r];
  }
}

extern "C" void kernel_launch(void* const* d_in, const int* in_sizes, int n_in,
                              void* d_out, int out_size, void* d_ws, size_t ws_size,
                              hipStream_t stream) {
  const float* x  = (const float*)d_in[0];   // (2048, 16384)
  const float* xh = (const float*)d_in[1];   // (2048, 16384)
  const float* h  = (const float*)d_in[2];   // (2048, 512) -- only row 0 used
  const float* Ww = (const float*)d_in[3];   // (5, 512)
  const float* Wb = (const float*)d_in[4];   // (5,)
  float* out = (float*)d_out;                // (2048, 8192)

  unsigned short* FXfrag = (unsigned short*)d_ws;        // 8192 bf16 = 16 KB
  unsigned short* FYfrag = FXfrag + 4 * 4 * 64 * 8;      // 8192 bf16 = 16 KB

  fb_setup_kernel<<<1, 512, 0, stream>>>(h, Ww, Wb, FXfrag, FYfrag);
  glimpse_kernel<<<4096, 256, 0, stream>>>(x, xh, FXfrag, FYfrag, out);
}

// Round 3
// 311.641 us; speedup vs baseline: 1.6966x; 1.0056x over previous
//
#include <hip/hip_runtime.h>
#include <math.h>

#define A_DIM 128   // image height/width
#define N_G   64    // glimpse size
#define HD    512   // h_dim

typedef short short8 __attribute__((ext_vector_type(8)));   // 8 bf16 = 4 VGPRs (MFMA A/B frag)
typedef float floatx4 __attribute__((ext_vector_type(4)));  // MFMA C/D frag

static __device__ __forceinline__ unsigned short f2bf(float f) {
  union { float f; unsigned u; } v; v.f = f;
  unsigned r = (v.u + 0x7fffu + ((v.u >> 16) & 1u)) >> 16;   // RNE
  return (unsigned short)r;
}

static __device__ __forceinline__ short8 pack8(float4 a, float4 b) {
  short8 r;
  r[0] = (short)f2bf(a.x); r[1] = (short)f2bf(a.y);
  r[2] = (short)f2bf(a.z); r[3] = (short)f2bf(a.w);
  r[4] = (short)f2bf(b.x); r[5] = (short)f2bf(b.y);
  r[6] = (short)f2bf(b.z); r[7] = (short)f2bf(b.w);
  return r;
}

// Builds pre-swizzled MFMA fragment tables in d_ws:
//  FXfrag[tile][kk][lane][j] = FX[m = tile*16 + (lane&15)][c = kk*32 + (lane>>4)*8 + j] / sumX
//  FYfrag[tile][kk][lane][j] = gamma * FY[n = ...][a = ...] / sumY
__global__ __launch_bounds__(512) void fb_setup_kernel(
    const float* __restrict__ h, const float* __restrict__ Ww,
    const float* __restrict__ Wb, unsigned short* __restrict__ FXfrag,
    unsigned short* __restrict__ FYfrag) {
  __shared__ float p[5];
  __shared__ float redX[8], redY[8];
  __shared__ float invs[2];
  const int tid = threadIdx.x, wave = tid >> 6, lane = tid & 63;

  if (wave < 5) {
    float s = 0.f;
    for (int k = lane; k < HD; k += 64) s += h[k] * Ww[wave * HD + k];
#pragma unroll
    for (int off = 32; off > 0; off >>= 1) s += __shfl_down(s, off);
    if (lane == 0) p[wave] = s + Wb[wave];
  }
  __syncthreads();

  const float gX = 64.5f * (p[0] + 1.0f);
  const float gY = 64.5f * (p[1] + 1.0f);
  const float var = expf(p[2] + 1e-8f);
  const float dd = expf(p[3]) * (127.0f / 63.0f);
  const float gamma = expf(p[4]);
  const float two_var = 2.0f * var;

  float sX = 0.f, sY = 0.f;
  for (int i = tid; i < N_G * A_DIM; i += 512) {
    const int n = i >> 7, a = i & 127;
    const float off_n = ((float)n - 32.5f) * dd;
    const float tx = (float)a - (gX + off_n);
    const float ty = (float)a - (gY + off_n);
    sX += expf(-(tx * tx) / two_var);
    sY += expf(-(ty * ty) / two_var);
  }
#pragma unroll
  for (int off = 32; off > 0; off >>= 1) {
    sX += __shfl_down(sX, off);
    sY += __shfl_down(sY, off);
  }
  if (lane == 0) { redX[wave] = sX; redY[wave] = sY; }
  __syncthreads();
  if (tid == 0) {
    float tX = 0.f, tY = 0.f;
#pragma unroll
    for (int w = 0; w < 8; ++w) { tX += redX[w]; tY += redY[w]; }
    invs[0] = 1.0f / tX;
    invs[1] = gamma / tY;
  }
  __syncthreads();
  const float isX = invs[0], isYg = invs[1];

  // 8192 fragment elements per table: i = tile*2048 + kk*512 + lane*8 + j
  for (int i = tid; i < 4 * 4 * 64 * 8; i += 512) {
    const int j = i & 7;
    const int ln = (i >> 3) & 63;
    const int kk = (i >> 9) & 3;
    const int tl = (i >> 11) & 3;
    const int mn = tl * 16 + (ln & 15);
    const int ca = kk * 32 + ((ln >> 4) << 3) + j;
    const float off_mn = ((float)mn - 32.5f) * dd;
    const float tx = (float)ca - (gX + off_mn);
    const float ty = (float)ca - (gY + off_mn);
    FXfrag[i] = f2bf(expf(-(tx * tx) / two_var) * isX);
    FYfrag[i] = f2bf(expf(-(ty * ty) / two_var) * isYg);
  }
}

// One block (256 thr, 4 waves) per (batch, tensor) image.
// Phase A: U[a][m] = sum_c x[a][c] * FX[m][c]   (A-frags straight from global fp32)
//          -> U^T[m][a] bf16 in LDS, XOR-swizzled 16-B chunks
// Phase B: out[n][m] = sum_a FY[n][a] * U[a][m]
__global__ __launch_bounds__(256, 4) void glimpse_kernel(
    const float* __restrict__ x, const float* __restrict__ xh,
    const unsigned short* __restrict__ FXfrag,
    const unsigned short* __restrict__ FYfrag,
    float* __restrict__ out) {
  const int img = blockIdx.x;
  const int b = img >> 1, t = img & 1;
  const float* __restrict__ src = (t ? xh : x) + (size_t)b * (A_DIM * A_DIM);
  float* __restrict__ dst = out + (size_t)b * (2 * N_G * N_G) + t * (N_G * N_G);

  // us[m][a]: 64 rows x 128 bf16 (256 B/row). Chunk = 8 elems (16 B); chunk
  // index ch stored at position (ch ^ lm) within the row -> b64 writes ~2-way
  // (free), b128 reads uniform over bank-quads.
  __shared__ __align__(16) unsigned short us[N_G * A_DIM];

  const int tid = threadIdx.x;
  const int w = tid >> 6, lane = tid & 63;
  const int quad = lane >> 4, lm = lane & 15;

  // ---- phase A ----
  {
    const float4* __restrict__ src4 = (const float4*)src;
    short8 aF[2][4];
#pragma unroll
    for (int i = 0; i < 2; ++i) {
      float4 u0[4], u1[4];
#pragma unroll
      for (int kk = 0; kk < 4; ++kk) {
        const int idx = ((2 * w + i) * 16 + lm) * 32 + kk * 8 + quad * 2;
        u0[kk] = src4[idx];
        u1[kk] = src4[idx + 1];
      }
#pragma unroll
      for (int kk = 0; kk < 4; ++kk) aF[i][kk] = pack8(u0[kk], u1[kk]);
    }

    floatx4 acc[2][4];
#pragma unroll
    for (int i = 0; i < 2; ++i)
#pragma unroll
      for (int j = 0; j < 4; ++j) acc[i][j] = (floatx4)0.f;

#pragma unroll
    for (int kk = 0; kk < 4; ++kk) {
      short8 bF[4];
#pragma unroll
      for (int j = 0; j < 4; ++j)
        bF[j] = *(const short8*)(FXfrag + ((size_t)(j * 4 + kk) * 64 + lane) * 8);
#pragma unroll
      for (int i = 0; i < 2; ++i)
#pragma unroll
        for (int j = 0; j < 4; ++j)
          acc[i][j] = __builtin_amdgcn_mfma_f32_16x16x32_bf16(aF[i][kk], bF[j], acc[i][j], 0, 0, 0);
    }

    // write U^T: lane holds (a = (2w+i)*16 + quad*4 + r, m = j*16 + lm)
#pragma unroll
    for (int i = 0; i < 2; ++i) {
      const int ch = (2 * w + i) * 2 + (quad >> 1);   // 16-B chunk index along a
      const int half = (quad & 1) * 4;                // 8-B half within chunk
#pragma unroll
      for (int j = 0; j < 4; ++j) {
        uint2 pk;
        pk.x = (unsigned)f2bf(acc[i][j][0]) | ((unsigned)f2bf(acc[i][j][1]) << 16);
        pk.y = (unsigned)f2bf(acc[i][j][2]) | ((unsigned)f2bf(acc[i][j][3]) << 16);
        *(uint2*)&us[(j * 16 + lm) * A_DIM + ((ch ^ lm) << 3) + half] = pk;
      }
    }
  }
  __syncthreads();

  // ---- phase B: wave w owns n-tile w, all 4 m-tiles ----
  {
    floatx4 acc2[4];
#pragma unroll
    for (int j = 0; j < 4; ++j) acc2[j] = (floatx4)0.f;

#pragma unroll
    for (int kk = 0; kk < 4; ++kk) {
      const short8 aF = *(const short8*)(FYfrag + ((size_t)(w * 4 + kk) * 64 + lane) * 8);
#pragma unroll
      for (int mt = 0; mt < 4; ++mt) {
        const int ch = (kk * 4 + quad) ^ lm;          // swizzled chunk position
        const short8 bF = *(const short8*)&us[(mt * 16 + lm) * A_DIM + (ch << 3)];
        acc2[mt] = __builtin_amdgcn_mfma_f32_16x16x32_bf16(aF, bF, acc2[mt], 0, 0, 0);
      }
    }

#pragma unroll
    for (int mt = 0; mt < 4; ++mt)
#pragma unroll
      for (int r = 0; r < 4; ++r)
        dst[(w * 16 + quad * 4 + r) * N_G + mt * 16 + lm] = acc2[mt][r];
  }
}

extern "C" void kernel_launch(void* const* d_in, const int* in_sizes, int n_in,
                              void* d_out, int out_size, void* d_ws, size_t ws_size,
                              hipStream_t stream) {
  const float* x  = (const float*)d_in[0];   // (2048, 16384)
  const float* xh = (const float*)d_in[1];   // (2048, 16384)
  const float* h  = (const float*)d_in[2];   // (2048, 512) -- only row 0 used
  const float* Ww = (const float*)d_in[3];   // (5, 512)
  const float* Wb = (const float*)d_in[4];   // (5,)
  float* out = (float*)d_out;                // (2048, 8192)

  unsigned short* FXfrag = (unsigned short*)d_ws;        // 8192 bf16 = 16 KB
  unsigned short* FYfrag = FXfrag + 4 * 4 * 64 * 8;      // 8192 bf16 = 16 KB

  fb_setup_kernel<<<1, 512, 0, stream>>>(h, Ww, Wb, FXfrag, FYfrag);
  glimpse_kernel<<<4096, 256, 0, stream>>>(x, xh, FXfrag, FYfrag, out);
}